// Round 6
// baseline (62.276 us; speedup 1.0000x reference)
//
#include <hip/hip_runtime.h>
#include <hip/hip_bf16.h>

#define NNODES 50000
#define DEG 16
#define NEDGES (NNODES * DEG)
#define IND 512
#define OUTD 128

#define BM 64           // gemm rows per block
#define CK 64           // K chunk
#define NCH 8           // 512 / 64
#define NB 64           // nodes per block in edge kernel
#define SROWS 80        // staged h rows per block (NB + DEG)

typedef __attribute__((ext_vector_type(8))) short bf16x8;
typedef __attribute__((ext_vector_type(4))) float f32x4;

static __device__ __forceinline__ unsigned short f2bf(float f) {
    unsigned u = __builtin_bit_cast(unsigned, f);
    u += 0x7fffu + ((u >> 16) & 1u);
    return (unsigned short)(u >> 16);
}

static __device__ __forceinline__ bf16x8 pack8(float4 a, float4 b) {
    union { unsigned u[4]; bf16x8 v; } r;
    r.u[0] = (unsigned)f2bf(a.x) | ((unsigned)f2bf(a.y) << 16);
    r.u[1] = (unsigned)f2bf(a.z) | ((unsigned)f2bf(a.w) << 16);
    r.u[2] = (unsigned)f2bf(b.x) | ((unsigned)f2bf(b.y) << 16);
    r.u[3] = (unsigned)f2bf(b.z) | ((unsigned)f2bf(b.w) << 16);
    return r.v;
}

// ---------------- kernel 0: W [512][128] f32 -> Wt [128][512] bf16 ----------------
__global__ __launch_bounds__(256) void wt_kernel(const float* __restrict__ W,
                                                 unsigned short* __restrict__ Wt) {
    int flat = blockIdx.x * 256 + threadIdx.x;   // 16384 = 128 n * 128 k4
    int n  = flat >> 7;
    int k4 = flat & 127;
    int k0 = k4 * 4;
    unsigned short v0 = f2bf(W[(k0 + 0) * OUTD + n]);
    unsigned short v1 = f2bf(W[(k0 + 1) * OUTD + n]);
    unsigned short v2 = f2bf(W[(k0 + 2) * OUTD + n]);
    unsigned short v3 = f2bf(W[(k0 + 3) * OUTD + n]);
    uint2 o;
    o.x = (unsigned)v0 | ((unsigned)v1 << 16);
    o.y = (unsigned)v2 | ((unsigned)v3 << 16);
    *reinterpret_cast<uint2*>(&Wt[n * IND + k0]) = o;
}

// ---------------- kernel 1: h = x @ W  (bf16 MFMA, f32 accum) ----------------
// BM=64 x 128 cols; waves split cols (each 64r x 32c, mt=4 nt=2).
// A: global f32 -> regs (prefetch 1 chunk ahead) -> pack bf16 -> ds_write (8 KB/buf).
// B: gload_lds bf16 from Wt, pre-swizzled source (16 KB/buf).
// Double-buffered, ONE raw s_barrier per chunk, counted vmcnt(4) (never 0 in loop).
// LDS 48 KB -> 3 blocks/CU.
__global__ __launch_bounds__(256, 3) void gemm_kernel(const float* __restrict__ x,
                                                      const unsigned short* __restrict__ Wt,
                                                      float* __restrict__ h) {
    __shared__ __align__(16) unsigned char lds_[49152];   // A 2x8K @0, B 2x16K @16384

    const int tid  = threadIdx.x;
    const int lane = tid & 63;
    const int wid  = tid >> 6;
    const int l15  = lane & 15;
    const int kg   = lane >> 4;
    const int base = blockIdx.x * BM;
    const int wc   = wid * 32;        // wave's col base

    // A reg-staging map: thread -> row = tid>>2, granule pair ag0, ag0+1 (16 f32)
    const int ar  = tid >> 2;
    const int ag0 = (tid & 3) * 2;
    int agr = base + ar; if (agr > NNODES - 1) agr = NNODES - 1;
    const float* axp = &x[(size_t)agr * IND + ag0 * 8];

    f32x4 acc[4][2];
#pragma unroll
    for (int mt = 0; mt < 4; ++mt)
#pragma unroll
        for (int nt = 0; nt < 2; ++nt) acc[mt][nt] = (f32x4){0.f, 0.f, 0.f, 0.f};

    float4 rA[2][4];

    auto stageB = [&](int buf, int ch) {
#pragma unroll
        for (int p = 0; p < 4; ++p) {
            int f   = p * 256 + tid;          // 1024 granules: col = f>>3, slot f&7
            int col = f >> 3;
            int g   = (f & 7) ^ (col & 7);    // pre-swizzled SOURCE (dest linear)
            const unsigned short* gp = &Wt[(size_t)col * IND + ch * CK + g * 8];
            unsigned char* lp = &lds_[16384 + (size_t)buf * 16384 + (size_t)f * 16];
            __builtin_amdgcn_global_load_lds((const unsigned int*)gp, (unsigned int*)lp, 16, 0, 0);
        }
    };

    // prologue: A(0) regs + B(0) lds
    {
        const float* p = axp;
        rA[0][0] = *reinterpret_cast<const float4*>(p);
        rA[0][1] = *reinterpret_cast<const float4*>(p + 4);
        rA[0][2] = *reinterpret_cast<const float4*>(p + 8);
        rA[0][3] = *reinterpret_cast<const float4*>(p + 12);
    }
    stageB(0, 0);

#pragma unroll
    for (int ch = 0; ch < NCH; ++ch) {
        const int par = ch & 1;
        if (ch < NCH - 1) {
            const float* p = axp + (ch + 1) * CK;
            rA[par ^ 1][0] = *reinterpret_cast<const float4*>(p);
            rA[par ^ 1][1] = *reinterpret_cast<const float4*>(p + 4);
            rA[par ^ 1][2] = *reinterpret_cast<const float4*>(p + 8);
            rA[par ^ 1][3] = *reinterpret_cast<const float4*>(p + 12);
            asm volatile("s_waitcnt vmcnt(4)" ::: "memory");   // A(ch),B(ch) done; A(ch+1) in flight
        } else {
            asm volatile("s_waitcnt vmcnt(0)" ::: "memory");
        }

        // pack + ds_write A(ch) -> buf par (safe: compute(ch-2) done at barrier ch-1)
        {
            bf16x8 q0 = pack8(rA[par][0], rA[par][1]);
            bf16x8 q1 = pack8(rA[par][2], rA[par][3]);
            unsigned char* aw = &lds_[(size_t)par * 8192 + (size_t)ar * 128];
            *reinterpret_cast<bf16x8*>(aw + ((ag0 ^ (ar & 7)) * 16))       = q0;
            *reinterpret_cast<bf16x8*>(aw + (((ag0 + 1) ^ (ar & 7)) * 16)) = q1;
        }
        asm volatile("s_waitcnt lgkmcnt(0)" ::: "memory");
        __builtin_amdgcn_s_barrier();
        asm volatile("" ::: "memory");
        __builtin_amdgcn_sched_barrier(0);

        if (ch < NCH - 1) stageB(par ^ 1, ch + 1);   // next B in flight across compute

        const unsigned char* Ab = &lds_[(size_t)par * 8192];
        const unsigned char* Bb = &lds_[16384 + (size_t)par * 16384];
#pragma unroll
        for (int ks = 0; ks < 2; ++ks) {
            bf16x8 af[4], bfv[2];
#pragma unroll
            for (int mt = 0; mt < 4; ++mt) {
                int row = mt * 16 + l15;
                af[mt] = *reinterpret_cast<const bf16x8*>(
                    Ab + row * 128 + (((ks * 4 + kg) ^ (row & 7)) * 16));
            }
#pragma unroll
            for (int nt = 0; nt < 2; ++nt) {
                int col = wc + nt * 16 + l15;
                bfv[nt] = *reinterpret_cast<const bf16x8*>(
                    Bb + col * 128 + (((ks * 4 + kg) ^ (col & 7)) * 16));
            }
#pragma unroll
            for (int mt = 0; mt < 4; ++mt)
#pragma unroll
                for (int nt = 0; nt < 2; ++nt)
                    acc[mt][nt] = __builtin_amdgcn_mfma_f32_16x16x32_bf16(af[mt], bfv[nt], acc[mt][nt], 0, 0, 0);
        }
    }

    // C/D layout: col = lane&15, row = (lane>>4)*4 + q
#pragma unroll
    for (int mt = 0; mt < 4; ++mt) {
#pragma unroll
        for (int q = 0; q < 4; ++q) {
            int grow = base + mt * 16 + kg * 4 + q;
            if (grow < NNODES) {
#pragma unroll
                for (int nt = 0; nt < 2; ++nt)
                    h[(size_t)grow * OUTD + wc + nt * 16 + l15] = acc[mt][nt][q];
            }
        }
    }
}

// ---------------- kernel 2: scores + segment softmax ----------------
__global__ __launch_bounds__(256) void edge_kernel(const float* __restrict__ h,
                                                   const float* __restrict__ a,
                                                   const int* __restrict__ eidx,
                                                   float* __restrict__ attn) {
    extern __shared__ __align__(16) unsigned char hl[];   // SROWS*512 = 40960 B

    const int tid  = threadIdx.x;
    const int base = blockIdx.x * NB;
    const int lane = tid & 63;
    const int wid  = tid >> 6;
    const int j    = lane >> 2;   // edge slot 0..15
    const int g    = lane & 3;    // dim group 0..3

    float4 a4[8];
#pragma unroll
    for (int c = 0; c < 8; ++c)
        a4[c] = *reinterpret_cast<const float4*>(&a[c * 16 + g * 4]);

    for (int p = 0; p < 10; ++p) {
        int f    = p * 256 + tid;         // 2560 16B-slots
        int row  = f >> 5;
        int blkp = f & 31;
        int blk  = blkp ^ ((row & 7) << 2);
        int gr   = base + row;
        if (gr >= NNODES) gr -= NNODES;
        float4 v = *reinterpret_cast<const float4*>(&h[(size_t)gr * OUTD + blk * 4]);
        *reinterpret_cast<float4*>(&hl[f * 16]) = v;
    }
    __syncthreads();

    const int* cols = eidx + NEDGES;
    for (int n = 0; n < 16; ++n) {
        int i = base + wid * 16 + n;
        if (i >= NNODES) break;           // wave-uniform
        int e   = i * DEG + j;
        int col = cols[e];
        int cr  = col - base;
        if (cr < 0) cr += NNODES;
        int ri = i - base;
        float s = 0.f;
        if (cr < SROWS) {
#pragma unroll
            for (int c = 0; c < 8; ++c) {
                int blk = c * 4 + g;
                float4 hi = *reinterpret_cast<const float4*>(&hl[ri * 512 + ((blk ^ ((ri & 7) << 2)) * 16)]);
                float4 hj = *reinterpret_cast<const float4*>(&hl[cr * 512 + ((blk ^ ((cr & 7) << 2)) * 16)]);
                s = fmaf(fabsf(hi.x - hj.x), a4[c].x, s);
                s = fmaf(fabsf(hi.y - hj.y), a4[c].y, s);
                s = fmaf(fabsf(hi.z - hj.z), a4[c].z, s);
                s = fmaf(fabsf(hi.w - hj.w), a4[c].w, s);
            }
        } else {
#pragma unroll
            for (int c = 0; c < 8; ++c) {
                int blk = c * 4 + g;
                float4 hi = *reinterpret_cast<const float4*>(&hl[ri * 512 + ((blk ^ ((ri & 7) << 2)) * 16)]);
                float4 hj = *reinterpret_cast<const float4*>(&h[(size_t)col * OUTD + blk * 4]);
                s = fmaf(fabsf(hi.x - hj.x), a4[c].x, s);
                s = fmaf(fabsf(hi.y - hj.y), a4[c].y, s);
                s = fmaf(fabsf(hi.z - hj.z), a4[c].z, s);
                s = fmaf(fabsf(hi.w - hj.w), a4[c].w, s);
            }
        }
        s += __shfl_xor(s, 1);
        s += __shfl_xor(s, 2);
        s = fmaxf(s, 0.f);
        float m = s;
        m = fmaxf(m, __shfl_xor(m, 4));
        m = fmaxf(m, __shfl_xor(m, 8));
        m = fmaxf(m, __shfl_xor(m, 16));
        m = fmaxf(m, __shfl_xor(m, 32));
        float pv = __expf(s - m);
        float S = pv;
        S += __shfl_xor(S, 4);
        S += __shfl_xor(S, 8);
        S += __shfl_xor(S, 16);
        S += __shfl_xor(S, 32);
        if (g == 0) attn[e] = pv / S;
    }
}

extern "C" void kernel_launch(void* const* d_in, const int* in_sizes, int n_in,
                              void* d_out, int out_size, void* d_ws, size_t ws_size,
                              hipStream_t stream) {
    const float* x  = (const float*)d_in[0];
    const float* W  = (const float*)d_in[1];
    const float* a  = (const float*)d_in[2];
    const int* eidx = (const int*)d_in[3];
    float* h    = (float*)d_out;
    float* attn = h + (size_t)NNODES * OUTD;
    unsigned short* Wt = (unsigned short*)d_ws;   // 128 KB scratch

    hipLaunchKernelGGL(wt_kernel, dim3(64), dim3(256), 0, stream, W, Wt);
    hipLaunchKernelGGL(gemm_kernel, dim3((NNODES + BM - 1) / BM), dim3(256), 0, stream, x, Wt, h);
    hipLaunchKernelGGL(edge_kernel, dim3((NNODES + NB - 1) / NB), dim3(256), SROWS * 512, stream,
                       h, a, eidx, attn);
}